// Round 1
// baseline (322.033 us; speedup 1.0000x reference)
//
#include <hip/hip_runtime.h>

#define BATCH 4
#define NS 4096
#define NA 1024
#define DIM 256
#define NH 8
#define HD 32

typedef float f32x4 __attribute__((ext_vector_type(4)));
typedef __bf16 bf16x8 __attribute__((ext_vector_type(8)));
typedef unsigned short u16x8 __attribute__((ext_vector_type(8)));
typedef unsigned int u32x4 __attribute__((ext_vector_type(4)));

__device__ inline unsigned short f2bf(float f) {
  unsigned int u = __builtin_bit_cast(unsigned int, f);
  u = (u + 0x7FFFu + ((u >> 16) & 1u)) >> 16;
  return (unsigned short)u;
}

__device__ inline f32x4 ld_f4(const float* p) {
  return *reinterpret_cast<const f32x4*>(p);
}

__device__ inline bf16x8 cvt_bf8(f32x4 a, f32x4 b) {
  u16x8 r;
  r[0] = f2bf(a[0]); r[1] = f2bf(a[1]); r[2] = f2bf(a[2]); r[3] = f2bf(a[3]);
  r[4] = f2bf(b[0]); r[5] = f2bf(b[1]); r[6] = f2bf(b[2]); r[7] = f2bf(b[3]);
  return __builtin_bit_cast(bf16x8, r);
}

__device__ inline bf16x8 ld_bf8(const unsigned short* p) {
  return __builtin_bit_cast(bf16x8, *reinterpret_cast<const u32x4*>(p));
}

__device__ inline f32x4 mfma16(bf16x8 a, bf16x8 b, f32x4 c) {
  return __builtin_amdgcn_mfma_f32_16x16x32_bf16(a, b, c, 0, 0, 0);
}

// ---------------------------------------------------------------------------
// Projection: out = X @ W^T + bias   (X: [B*Ntok, 256] f32, W: [256,256] f32)
// MODE 0: out bf16 at [(b*NH+h)*Ntok + tok]*HD + d     (Q and K)
// MODE 1: out bf16 at [(b*NH+h)*HD + d]*NA + tok       (V transposed)
// Block = 4 waves, covers 16 rows x 256 cols. Each wave: 16 rows x 64 cols.
// ---------------------------------------------------------------------------
template<int MODE>
__global__ __launch_bounds__(256)
void proj_qkv(const float* __restrict__ X, const float* __restrict__ W,
              const float* __restrict__ bias, unsigned short* __restrict__ out,
              int Ntok)
{
  const int r0 = blockIdx.x * 16;
  const int tid = threadIdx.x;
  const int wave = tid >> 6, lane = tid & 63, g = lane >> 4, c = lane & 15;
  const int nb = wave * 64;

  f32x4 acc[4] = {};
#pragma unroll
  for (int ks = 0; ks < 8; ++ks) {
    const int k0 = ks * 32 + g * 8;
    const float* xp = X + (size_t)(r0 + c) * DIM + k0;
    bf16x8 af = cvt_bf8(ld_f4(xp), ld_f4(xp + 4));
#pragma unroll
    for (int nt = 0; nt < 4; ++nt) {
      const float* wp = W + (size_t)(nb + nt * 16 + c) * DIM + k0;
      bf16x8 bf = cvt_bf8(ld_f4(wp), ld_f4(wp + 4));
      acc[nt] = mfma16(af, bf, acc[nt]);
    }
  }
  const int b = r0 / Ntok;
  const int t0 = r0 % Ntok;
#pragma unroll
  for (int nt = 0; nt < 4; ++nt) {
#pragma unroll
    for (int i = 0; i < 4; ++i) {
      const int row = g * 4 + i;            // C layout: row=(lane>>4)*4+reg
      const int n = nb + nt * 16 + c;       //           col=lane&15
      const float v = acc[nt][i] + bias[n];
      const int h = n >> 5, d = n & 31;
      size_t idx;
      if (MODE == 0) idx = ((size_t)(b * NH + h) * Ntok + (t0 + row)) * HD + d;
      else           idx = ((size_t)(b * NH + h) * HD + d) * NA + (t0 + row);
      out[idx] = f2bf(v);
    }
  }
}

// ---------------------------------------------------------------------------
// Attention: per block = one (b,h), 16 s-rows. 4 waves x 256 a-cols each.
// scores (MFMA f32) -> softmax (shuffle + LDS cross-wave) -> write P f32 to
// d_out -> P bf16 to LDS -> PV (MFMA) -> cross-wave reduce -> attended bf16.
// ---------------------------------------------------------------------------
__global__ __launch_bounds__(256)
void attn_kernel(const unsigned short* __restrict__ Qb,
                 const unsigned short* __restrict__ Kb,
                 const unsigned short* __restrict__ Vt,
                 float* __restrict__ attn_out,
                 unsigned short* __restrict__ attw)
{
  __shared__ unsigned short P_lds[16][1032];  // +8 pad: 2-way bank alias only
  __shared__ float att_p[4][16][32];
  __shared__ float wred[4][16];

  const int blk = blockIdx.x;
  const int bh = blk >> 8;             // NS/16 = 256 row-tiles per (b,h)
  const int s0 = (blk & 255) << 4;
  const int tid = threadIdx.x;
  const int wave = tid >> 6, lane = tid & 63, g = lane >> 4, c = lane & 15;
  const float scale = 0.17677669529663687f;  // 1/sqrt(32)

  const unsigned short* Qp = Qb + ((size_t)bh * NS + s0) * HD;
  const unsigned short* Kp = Kb + (size_t)bh * NA * HD;
  const unsigned short* Vp = Vt + (size_t)bh * HD * NA;

  // Q fragment: A[m=lane&15][k=(lane>>4)*8 + j], hd=32 = one MFMA K
  const bf16x8 qf = ld_bf8(Qp + (size_t)c * HD + g * 8);

  const int ab = wave * 256;
  f32x4 acc[16];
#pragma unroll
  for (int nt = 0; nt < 16; ++nt) {
    bf16x8 kf = ld_bf8(Kp + (size_t)(ab + nt * 16 + c) * HD + g * 8);
    f32x4 z = {0.f, 0.f, 0.f, 0.f};
    acc[nt] = mfma16(qf, kf, z);
  }

  // scale + per-row max over this wave's 256 cols
  float rmax[4] = {-1e30f, -1e30f, -1e30f, -1e30f};
#pragma unroll
  for (int nt = 0; nt < 16; ++nt)
#pragma unroll
    for (int i = 0; i < 4; ++i) {
      acc[nt][i] *= scale;
      rmax[i] = fmaxf(rmax[i], acc[nt][i]);
    }
#pragma unroll
  for (int off = 1; off < 16; off <<= 1)
#pragma unroll
    for (int i = 0; i < 4; ++i)
      rmax[i] = fmaxf(rmax[i], __shfl_xor(rmax[i], off));
  if (c == 0) {
#pragma unroll
    for (int i = 0; i < 4; ++i) wred[wave][g * 4 + i] = rmax[i];
  }
  __syncthreads();
  float gmax[4];
#pragma unroll
  for (int i = 0; i < 4; ++i) {
    const int r = g * 4 + i;
    gmax[i] = fmaxf(fmaxf(wred[0][r], wred[1][r]), fmaxf(wred[2][r], wred[3][r]));
  }
  __syncthreads();

  // exp + per-row sum
  float rsum[4] = {0.f, 0.f, 0.f, 0.f};
#pragma unroll
  for (int nt = 0; nt < 16; ++nt)
#pragma unroll
    for (int i = 0; i < 4; ++i) {
      const float p = __expf(acc[nt][i] - gmax[i]);
      acc[nt][i] = p;
      rsum[i] += p;
    }
#pragma unroll
  for (int off = 1; off < 16; off <<= 1)
#pragma unroll
    for (int i = 0; i < 4; ++i)
      rsum[i] += __shfl_xor(rsum[i], off);
  if (c == 0) {
#pragma unroll
    for (int i = 0; i < 4; ++i) wred[wave][g * 4 + i] = rsum[i];
  }
  __syncthreads();
  float inv[4];
#pragma unroll
  for (int i = 0; i < 4; ++i) {
    const int r = g * 4 + i;
    inv[i] = 1.0f / (wred[0][r] + wred[1][r] + wred[2][r] + wred[3][r]);
  }

  // normalize; write P to global (f32) and LDS (bf16, A-frag layout for PV)
  float* aout = attn_out + ((size_t)bh * NS + s0) * NA;
#pragma unroll
  for (int nt = 0; nt < 16; ++nt)
#pragma unroll
    for (int i = 0; i < 4; ++i) {
      const int row = g * 4 + i, col = ab + nt * 16 + c;
      const float p = acc[nt][i] * inv[i];
      aout[(size_t)row * NA + col] = p;
      P_lds[row][col] = f2bf(p);
    }
  __syncthreads();

  // PV: each wave covers its own 256-wide a-range (8 k-steps of 32)
  f32x4 o0 = {}, o1 = {};
#pragma unroll
  for (int ks = 0; ks < 8; ++ks) {
    const int k0 = ab + ks * 32 + g * 8;
    bf16x8 pf = ld_bf8(&P_lds[c][k0]);
    bf16x8 v0 = ld_bf8(Vp + (size_t)c * NA + k0);
    bf16x8 v1 = ld_bf8(Vp + (size_t)(16 + c) * NA + k0);
    o0 = mfma16(pf, v0, o0);
    o1 = mfma16(pf, v1, o1);
  }
#pragma unroll
  for (int i = 0; i < 4; ++i) {
    att_p[wave][g * 4 + i][c] = o0[i];
    att_p[wave][g * 4 + i][16 + c] = o1[i];
  }
  __syncthreads();

  const int b = bh >> 3, h = bh & 7;
  for (int t = tid; t < 512; t += 256) {
    const int row = t >> 5, col = t & 31;
    const float s = att_p[0][row][col] + att_p[1][row][col] +
                    att_p[2][row][col] + att_p[3][row][col];
    attw[((size_t)b * NS + s0 + row) * DIM + h * HD + col] = f2bf(s);
  }
}

// ---------------------------------------------------------------------------
// Output projection + residual + LayerNorm, fused.
// ---------------------------------------------------------------------------
__global__ __launch_bounds__(256)
void out_proj_ln(const unsigned short* __restrict__ attw,
                 const float* __restrict__ sat,
                 const float* __restrict__ Wo, const float* __restrict__ bo,
                 const float* __restrict__ gamma, const float* __restrict__ beta,
                 float* __restrict__ out)
{
  __shared__ float Y[16][DIM];
  const int r0 = blockIdx.x * 16;
  const int tid = threadIdx.x;
  const int wave = tid >> 6, lane = tid & 63, g = lane >> 4, c = lane & 15;
  const int nb = wave * 64;

  f32x4 acc[4] = {};
#pragma unroll
  for (int ks = 0; ks < 8; ++ks) {
    const int k0 = ks * 32 + g * 8;
    bf16x8 af = ld_bf8(attw + (size_t)(r0 + c) * DIM + k0);
#pragma unroll
    for (int nt = 0; nt < 4; ++nt) {
      const float* wp = Wo + (size_t)(nb + nt * 16 + c) * DIM + k0;
      bf16x8 bf = cvt_bf8(ld_f4(wp), ld_f4(wp + 4));
      acc[nt] = mfma16(af, bf, acc[nt]);
    }
  }
#pragma unroll
  for (int nt = 0; nt < 4; ++nt)
#pragma unroll
    for (int i = 0; i < 4; ++i) {
      const int row = g * 4 + i, n = nb + nt * 16 + c;
      Y[row][n] = acc[nt][i] + bo[n] + sat[(size_t)(r0 + row) * DIM + n];
    }
  __syncthreads();

  // LayerNorm: 16 threads per row, 16 elems each (4x float4, coalesced)
  const int row = tid >> 4, tt = tid & 15;
  f32x4 v[4];
  float s = 0.f, ss = 0.f;
#pragma unroll
  for (int j = 0; j < 4; ++j) {
    v[j] = *reinterpret_cast<const f32x4*>(&Y[row][tt * 4 + 64 * j]);
#pragma unroll
    for (int e = 0; e < 4; ++e) { s += v[j][e]; ss += v[j][e] * v[j][e]; }
  }
#pragma unroll
  for (int off = 1; off < 16; off <<= 1) {
    s += __shfl_xor(s, off);
    ss += __shfl_xor(ss, off);
  }
  const float mu = s * (1.0f / 256.0f);
  const float var = ss * (1.0f / 256.0f) - mu * mu;
  const float rstd = rsqrtf(var + 1e-5f);
  float* op = out + (size_t)(r0 + row) * DIM;
#pragma unroll
  for (int j = 0; j < 4; ++j) {
    const int n0 = tt * 4 + 64 * j;
    f32x4 r;
#pragma unroll
    for (int e = 0; e < 4; ++e)
      r[e] = (v[j][e] - mu) * rstd * gamma[n0 + e] + beta[n0 + e];
    *reinterpret_cast<f32x4*>(op + n0) = r;
  }
}

// ---------------------------------------------------------------------------
extern "C" void kernel_launch(void* const* d_in, const int* in_sizes, int n_in,
                              void* d_out, int out_size, void* d_ws, size_t ws_size,
                              hipStream_t stream)
{
  (void)in_sizes; (void)n_in; (void)out_size; (void)ws_size;
  const float* sat   = (const float*)d_in[0];
  const float* aux   = (const float*)d_in[1];
  const float* Wq    = (const float*)d_in[2];
  const float* bq    = (const float*)d_in[3];
  const float* Wk    = (const float*)d_in[4];
  const float* bk    = (const float*)d_in[5];
  const float* Wv    = (const float*)d_in[6];
  const float* bv    = (const float*)d_in[7];
  const float* Wo    = (const float*)d_in[8];
  const float* bo    = (const float*)d_in[9];
  const float* gamma = (const float*)d_in[10];
  const float* beta  = (const float*)d_in[11];

  float* out = (float*)d_out;                       // (B, NS, DIM) f32
  float* attn_out = out + (size_t)BATCH * NS * DIM; // (B, NH, NS, NA) f32

  // workspace: Qb 8MB | Kb 2MB | Vt 2MB | attw(bf16) 8MB  = 20 MB total
  char* ws = (char*)d_ws;
  unsigned short* Qb   = (unsigned short*)(ws);
  unsigned short* Kb   = (unsigned short*)(ws + (8u << 20));
  unsigned short* Vt   = (unsigned short*)(ws + (10u << 20));
  unsigned short* attw = (unsigned short*)(ws + (12u << 20));

  proj_qkv<0><<<dim3(BATCH * NS / 16), dim3(256), 0, stream>>>(sat, Wq, bq, Qb, NS);
  proj_qkv<0><<<dim3(BATCH * NA / 16), dim3(256), 0, stream>>>(aux, Wk, bk, Kb, NA);
  proj_qkv<1><<<dim3(BATCH * NA / 16), dim3(256), 0, stream>>>(aux, Wv, bv, Vt, NA);
  attn_kernel<<<dim3(BATCH * NH * (NS / 16)), dim3(256), 0, stream>>>(Qb, Kb, Vt, attn_out, attw);
  out_proj_ln<<<dim3(BATCH * NS / 16), dim3(256), 0, stream>>>(attw, sat, Wo, bo, gamma, beta, out);
}

// Round 2
// 250.612 us; speedup vs baseline: 1.2850x; 1.2850x over previous
//
#include <hip/hip_runtime.h>

#define BATCH 4
#define NS 4096
#define NA 1024
#define DIM 256
#define NH 8
#define HD 32

typedef float f32x4 __attribute__((ext_vector_type(4)));
typedef __bf16 bf16x8 __attribute__((ext_vector_type(8)));
typedef unsigned short u16x8 __attribute__((ext_vector_type(8)));
typedef unsigned short u16x4 __attribute__((ext_vector_type(4)));
typedef unsigned int u32x4 __attribute__((ext_vector_type(4)));

__device__ inline unsigned short f2bf(float f) {
  unsigned int u = __builtin_bit_cast(unsigned int, f);
  u = (u + 0x7FFFu + ((u >> 16) & 1u)) >> 16;
  return (unsigned short)u;
}

__device__ inline float bf2f(unsigned short u) {
  return __builtin_bit_cast(float, ((unsigned int)u) << 16);
}

__device__ inline f32x4 ld_f4(const float* p) {
  return *reinterpret_cast<const f32x4*>(p);
}

__device__ inline bf16x8 cvt_bf8(f32x4 a, f32x4 b) {
  u16x8 r;
  r[0] = f2bf(a[0]); r[1] = f2bf(a[1]); r[2] = f2bf(a[2]); r[3] = f2bf(a[3]);
  r[4] = f2bf(b[0]); r[5] = f2bf(b[1]); r[6] = f2bf(b[2]); r[7] = f2bf(b[3]);
  return __builtin_bit_cast(bf16x8, r);
}

__device__ inline bf16x8 ld_bf8(const unsigned short* p) {
  return __builtin_bit_cast(bf16x8, *reinterpret_cast<const u32x4*>(p));
}

__device__ inline f32x4 mfma16(bf16x8 a, bf16x8 b, f32x4 c) {
  return __builtin_amdgcn_mfma_f32_16x16x32_bf16(a, b, c, 0, 0, 0);
}

// ---------------------------------------------------------------------------
// Projection: out = X @ W^T + bias   (X: [B*Ntok, 256] f32, W: [256,256] f32)
// MODE 0: out bf16 at [(b*NH+h)*Ntok + tok]*HD + d     (Q and K)
// MODE 1: out bf16 at [(b*NH+h)*HD + d]*NA + tok       (V transposed)
// ---------------------------------------------------------------------------
template<int MODE>
__global__ __launch_bounds__(256)
void proj_qkv(const float* __restrict__ X, const float* __restrict__ W,
              const float* __restrict__ bias, unsigned short* __restrict__ out,
              int Ntok)
{
  const int r0 = blockIdx.x * 16;
  const int tid = threadIdx.x;
  const int wave = tid >> 6, lane = tid & 63, g = lane >> 4, c = lane & 15;
  const int nb = wave * 64;

  f32x4 acc[4] = {};
#pragma unroll
  for (int ks = 0; ks < 8; ++ks) {
    const int k0 = ks * 32 + g * 8;
    const float* xp = X + (size_t)(r0 + c) * DIM + k0;
    bf16x8 af = cvt_bf8(ld_f4(xp), ld_f4(xp + 4));
#pragma unroll
    for (int nt = 0; nt < 4; ++nt) {
      const float* wp = W + (size_t)(nb + nt * 16 + c) * DIM + k0;
      bf16x8 bf = cvt_bf8(ld_f4(wp), ld_f4(wp + 4));
      acc[nt] = mfma16(af, bf, acc[nt]);
    }
  }
  const int b = r0 / Ntok;
  const int t0 = r0 % Ntok;
#pragma unroll
  for (int nt = 0; nt < 4; ++nt) {
#pragma unroll
    for (int i = 0; i < 4; ++i) {
      const int row = g * 4 + i;            // C layout: row=(lane>>4)*4+reg
      const int n = nb + nt * 16 + c;       //           col=lane&15
      const float v = acc[nt][i] + bias[n];
      const int h = n >> 5, d = n & 31;
      size_t idx;
      if (MODE == 0) idx = ((size_t)(b * NH + h) * Ntok + (t0 + row)) * HD + d;
      else           idx = ((size_t)(b * NH + h) * HD + d) * NA + (t0 + row);
      out[idx] = f2bf(v);
    }
  }
}

// ---------------------------------------------------------------------------
// Attention: per block = one (b,h), 16 s-rows. 4 waves x 256 a-cols each.
// scores (MFMA) -> softmax -> P bf16 to LDS -> PV (MFMA) + coalesced
// nontemporal f32 P-write streamed from LDS (1KB/wave/instr).
// ---------------------------------------------------------------------------
__global__ __launch_bounds__(256)
void attn_kernel(const unsigned short* __restrict__ Qb,
                 const unsigned short* __restrict__ Kb,
                 const unsigned short* __restrict__ Vt,
                 float* __restrict__ attn_out,
                 unsigned short* __restrict__ attw)
{
  __shared__ unsigned short P_lds[16][1032];  // +8 pad: 2-way bank alias only
  __shared__ float att_p[4][16][32];
  __shared__ float wred[4][16];

  const int blk = blockIdx.x;
  const int bh = blk >> 8;             // NS/16 = 256 row-tiles per (b,h)
  const int s0 = (blk & 255) << 4;
  const int tid = threadIdx.x;
  const int wave = tid >> 6, lane = tid & 63, g = lane >> 4, c = lane & 15;
  // scale folded into exp: exp2((s-m) * scale*log2e)
  const float expc = 0.17677669529663687f * 1.4426950408889634f;

  const unsigned short* Qp = Qb + ((size_t)bh * NS + s0) * HD;
  const unsigned short* Kp = Kb + (size_t)bh * NA * HD;
  const unsigned short* Vp = Vt + (size_t)bh * HD * NA;

  // Q fragment: A[m=lane&15][k=(lane>>4)*8 + j], hd=32 = one MFMA K
  const bf16x8 qf = ld_bf8(Qp + (size_t)c * HD + g * 8);

  const int ab = wave * 256;
  f32x4 acc[16];
#pragma unroll
  for (int nt = 0; nt < 16; ++nt) {
    bf16x8 kf = ld_bf8(Kp + (size_t)(ab + nt * 16 + c) * HD + g * 8);
    f32x4 z = {0.f, 0.f, 0.f, 0.f};
    acc[nt] = mfma16(qf, kf, z);
  }

  // per-row max over this wave's 256 cols (raw scores; scale folded later)
  float rmax[4] = {-1e30f, -1e30f, -1e30f, -1e30f};
#pragma unroll
  for (int nt = 0; nt < 16; ++nt)
#pragma unroll
    for (int i = 0; i < 4; ++i)
      rmax[i] = fmaxf(rmax[i], acc[nt][i]);
#pragma unroll
  for (int off = 1; off < 16; off <<= 1)
#pragma unroll
    for (int i = 0; i < 4; ++i)
      rmax[i] = fmaxf(rmax[i], __shfl_xor(rmax[i], off));
  if (c == 0) {
#pragma unroll
    for (int i = 0; i < 4; ++i) wred[wave][g * 4 + i] = rmax[i];
  }
  __syncthreads();
  float gmax[4];
#pragma unroll
  for (int i = 0; i < 4; ++i) {
    const int r = g * 4 + i;
    gmax[i] = fmaxf(fmaxf(wred[0][r], wred[1][r]), fmaxf(wred[2][r], wred[3][r]));
  }
  __syncthreads();

  // exp + per-row sum
  float rsum[4] = {0.f, 0.f, 0.f, 0.f};
#pragma unroll
  for (int nt = 0; nt < 16; ++nt)
#pragma unroll
    for (int i = 0; i < 4; ++i) {
      const float p = exp2f((acc[nt][i] - gmax[i]) * expc);
      acc[nt][i] = p;
      rsum[i] += p;
    }
#pragma unroll
  for (int off = 1; off < 16; off <<= 1)
#pragma unroll
    for (int i = 0; i < 4; ++i)
      rsum[i] += __shfl_xor(rsum[i], off);
  if (c == 0) {
#pragma unroll
    for (int i = 0; i < 4; ++i) wred[wave][g * 4 + i] = rsum[i];
  }
  __syncthreads();
  float inv[4];
#pragma unroll
  for (int i = 0; i < 4; ++i) {
    const int r = g * 4 + i;
    inv[i] = 1.0f / (wred[0][r] + wred[1][r] + wred[2][r] + wred[3][r]);
  }

  // normalize -> P bf16 to LDS only (A-frag layout for PV; also the source
  // for the coalesced f32 global write below)
#pragma unroll
  for (int nt = 0; nt < 16; ++nt)
#pragma unroll
    for (int i = 0; i < 4; ++i)
      P_lds[g * 4 + i][ab + nt * 16 + c] = f2bf(acc[nt][i] * inv[i]);
  __syncthreads();

  // PV: each wave covers its own 256-wide a-range (8 k-steps of 32)
  f32x4 o0 = {}, o1 = {};
#pragma unroll
  for (int ks = 0; ks < 8; ++ks) {
    const int k0 = ab + ks * 32 + g * 8;
    bf16x8 pf = ld_bf8(&P_lds[c][k0]);
    bf16x8 v0 = ld_bf8(Vp + (size_t)c * NA + k0);
    bf16x8 v1 = ld_bf8(Vp + (size_t)(16 + c) * NA + k0);
    o0 = mfma16(pf, v0, o0);
    o1 = mfma16(pf, v1, o1);
  }
#pragma unroll
  for (int i = 0; i < 4; ++i) {
    att_p[wave][g * 4 + i][c] = o0[i];
    att_p[wave][g * 4 + i][16 + c] = o1[i];
  }

  // Coalesced P write: wave w streams rows 4w..4w+3; 64 lanes x float4 = 1KB
  // contiguous per store. Nontemporal: write-once data, keep out of L2.
  float* aout = attn_out + ((size_t)bh * NS + s0) * NA;
#pragma unroll
  for (int rr = 0; rr < 4; ++rr) {
    const int row = wave * 4 + rr;
#pragma unroll
    for (int p = 0; p < 4; ++p) {
      const int col = p * 256 + lane * 4;
      u16x4 raw = *reinterpret_cast<const u16x4*>(&P_lds[row][col]);
      f32x4 o;
      o[0] = bf2f(raw[0]); o[1] = bf2f(raw[1]);
      o[2] = bf2f(raw[2]); o[3] = bf2f(raw[3]);
      __builtin_nontemporal_store(o, reinterpret_cast<f32x4*>(aout + (size_t)row * NA + col));
    }
  }
  __syncthreads();

  const int b = bh >> 3, h = bh & 7;
  for (int t = tid; t < 512; t += 256) {
    const int row = t >> 5, col = t & 31;
    const float s = att_p[0][row][col] + att_p[1][row][col] +
                    att_p[2][row][col] + att_p[3][row][col];
    attw[((size_t)b * NS + s0 + row) * DIM + h * HD + col] = f2bf(s);
  }
}

// ---------------------------------------------------------------------------
// Output projection + residual + LayerNorm, fused.
// ---------------------------------------------------------------------------
__global__ __launch_bounds__(256)
void out_proj_ln(const unsigned short* __restrict__ attw,
                 const float* __restrict__ sat,
                 const float* __restrict__ Wo, const float* __restrict__ bo,
                 const float* __restrict__ gamma, const float* __restrict__ beta,
                 float* __restrict__ out)
{
  __shared__ float Y[16][DIM];
  const int r0 = blockIdx.x * 16;
  const int tid = threadIdx.x;
  const int wave = tid >> 6, lane = tid & 63, g = lane >> 4, c = lane & 15;
  const int nb = wave * 64;

  f32x4 acc[4] = {};
#pragma unroll
  for (int ks = 0; ks < 8; ++ks) {
    const int k0 = ks * 32 + g * 8;
    bf16x8 af = ld_bf8(attw + (size_t)(r0 + c) * DIM + k0);
#pragma unroll
    for (int nt = 0; nt < 4; ++nt) {
      const float* wp = Wo + (size_t)(nb + nt * 16 + c) * DIM + k0;
      bf16x8 bf = cvt_bf8(ld_f4(wp), ld_f4(wp + 4));
      acc[nt] = mfma16(af, bf, acc[nt]);
    }
  }
#pragma unroll
  for (int nt = 0; nt < 4; ++nt)
#pragma unroll
    for (int i = 0; i < 4; ++i) {
      const int row = g * 4 + i, n = nb + nt * 16 + c;
      Y[row][n] = acc[nt][i] + bo[n] + sat[(size_t)(r0 + row) * DIM + n];
    }
  __syncthreads();

  // LayerNorm: 16 threads per row, 16 elems each (4x float4, coalesced)
  const int row = tid >> 4, tt = tid & 15;
  f32x4 v[4];
  float s = 0.f, ss = 0.f;
#pragma unroll
  for (int j = 0; j < 4; ++j) {
    v[j] = *reinterpret_cast<const f32x4*>(&Y[row][tt * 4 + 64 * j]);
#pragma unroll
    for (int e = 0; e < 4; ++e) { s += v[j][e]; ss += v[j][e] * v[j][e]; }
  }
#pragma unroll
  for (int off = 1; off < 16; off <<= 1) {
    s += __shfl_xor(s, off);
    ss += __shfl_xor(ss, off);
  }
  const float mu = s * (1.0f / 256.0f);
  const float var = ss * (1.0f / 256.0f) - mu * mu;
  const float rstd = rsqrtf(var + 1e-5f);
  float* op = out + (size_t)(r0 + row) * DIM;
#pragma unroll
  for (int j = 0; j < 4; ++j) {
    const int n0 = tt * 4 + 64 * j;
    f32x4 r;
#pragma unroll
    for (int e = 0; e < 4; ++e)
      r[e] = (v[j][e] - mu) * rstd * gamma[n0 + e] + beta[n0 + e];
    *reinterpret_cast<f32x4*>(op + n0) = r;
  }
}

// ---------------------------------------------------------------------------
extern "C" void kernel_launch(void* const* d_in, const int* in_sizes, int n_in,
                              void* d_out, int out_size, void* d_ws, size_t ws_size,
                              hipStream_t stream)
{
  (void)in_sizes; (void)n_in; (void)out_size; (void)ws_size;
  const float* sat   = (const float*)d_in[0];
  const float* aux   = (const float*)d_in[1];
  const float* Wq    = (const float*)d_in[2];
  const float* bq    = (const float*)d_in[3];
  const float* Wk    = (const float*)d_in[4];
  const float* bk    = (const float*)d_in[5];
  const float* Wv    = (const float*)d_in[6];
  const float* bv    = (const float*)d_in[7];
  const float* Wo    = (const float*)d_in[8];
  const float* bo    = (const float*)d_in[9];
  const float* gamma = (const float*)d_in[10];
  const float* beta  = (const float*)d_in[11];

  float* out = (float*)d_out;                       // (B, NS, DIM) f32
  float* attn_out = out + (size_t)BATCH * NS * DIM; // (B, NH, NS, NA) f32

  // workspace: Qb 8MB | Kb 2MB | Vt 2MB | attw(bf16) 8MB  = 20 MB total
  char* ws = (char*)d_ws;
  unsigned short* Qb   = (unsigned short*)(ws);
  unsigned short* Kb   = (unsigned short*)(ws + (8u << 20));
  unsigned short* Vt   = (unsigned short*)(ws + (10u << 20));
  unsigned short* attw = (unsigned short*)(ws + (12u << 20));

  proj_qkv<0><<<dim3(BATCH * NS / 16), dim3(256), 0, stream>>>(sat, Wq, bq, Qb, NS);
  proj_qkv<0><<<dim3(BATCH * NA / 16), dim3(256), 0, stream>>>(aux, Wk, bk, Kb, NA);
  proj_qkv<1><<<dim3(BATCH * NA / 16), dim3(256), 0, stream>>>(aux, Wv, bv, Vt, NA);
  attn_kernel<<<dim3(BATCH * NH * (NS / 16)), dim3(256), 0, stream>>>(Qb, Kb, Vt, attn_out, attw);
  out_proj_ln<<<dim3(BATCH * NS / 16), dim3(256), 0, stream>>>(attw, sat, Wo, bo, gamma, beta, out);
}